// Round 8
// baseline (441.540 us; speedup 1.0000x reference)
//
#include <hip/hip_runtime.h>
#include <math.h>

#define B_ 4
#define C_ 256
#define RES_ 128
#define HW_ 16384
#define WF_ 65
#define F_ 8320
#define FP_ 2880   // packed masked-freq grid: 40 cols x 72 rows, fp = kx*72 + ky (covers runtime 36x71)

typedef __attribute__((ext_vector_type(8))) short bf16x8;
typedef __attribute__((ext_vector_type(16))) float f32x16;

__device__ __forceinline__ int brev6(int j){ return (int)(__brev((unsigned)j) >> 26); }

__device__ __forceinline__ short f2bf(float f){
  unsigned u = __float_as_uint(f);
  unsigned r = (u + 0x7FFFu + ((u>>16)&1u)) >> 16;
  return (short)r;
}

__device__ __forceinline__ bf16x8 lds_frag(const short* p){
  union { bf16x8 v; int2 d[2]; } u;
  u.d[0] = *(const int2*)p;
  u.d[1] = *(const int2*)(p+4);
  return u.v;
}
__device__ __forceinline__ void lds_store8(short* p, bf16x8 v){
  union { bf16x8 v; int2 d[2]; } u; u.v = v;
  *(int2*)p = u.d[0]; *(int2*)(p+4) = u.d[1];
}

// ---- band id, bit-exact vs numpy float32 ----
__device__ __forceinline__ int band_of(int row, int col){
  float yy = __fdiv_rn((float)row, 127.0f);
  float xx = __fdiv_rn((float)col, 64.0f);
  float rr = __fsqrt_rn(__fadd_rn(__fmul_rn(yy,yy), __fmul_rn(xx,xx)));
  float rm = __fadd_rn(__fsqrt_rn(2.0f), 1e-8f);
  float rn = __fdiv_rn(rr, rm);
  int b = (int)floorf(__fmul_rn(rn, 6.0f));
  return b > 5 ? 5 : b;
}

__device__ __forceinline__ float sigmoidf_(float v){ return 1.0f/(1.0f+expf(-v)); }

// ---- wave-synchronous 64-pt radix-2 DIF FFT, one complex value per lane ----
// Output bit-reversed across lanes: result for index r lives at lane brev6(r).
template<int SGN>
__device__ __forceinline__ float2 wave_fft64(float2 v, const float2* stw, int lane){
  #pragma unroll
  for (int s=0; s<6; s++){
    int H = 32 >> s;
    float ox = __shfl_xor(v.x, H);
    float oy = __shfl_xor(v.y, H);
    bool hi = (lane & H) != 0;
    float2 w = stw[s];
    float ws = (SGN < 0) ? -w.y : w.y;
    float sx = v.x + ox, sy = v.y + oy;
    float dx = ox - v.x, dy = oy - v.y;   // (a - b) on the hi lane
    float rx = dx*w.x - dy*ws;
    float ry = dx*ws + dy*w.x;
    v.x = hi ? rx : sx;
    v.y = hi ? ry : sy;
  }
  return v;
}

// per-lane stage twiddles: identical float values to a 128-entry table at even indices
__device__ __forceinline__ void make_stage_tw(float2* stw, int lane){
  #pragma unroll
  for (int s=0; s<6; s++){
    int H = 32 >> s;
    int t = (lane & (H-1)) << s;
    float sn, cs;
    sincosf(6.283185307179586f*(float)t/64.0f, &sn, &cs);
    stw[s] = make_float2(cs, sn);
  }
}

// redistribute (val[2l], val[2l+1]) per lane -> u0 = val[l], u1 = val[l+64]
__device__ __forceinline__ void redist2(float2 a0, float2 a1, int lane, float2& u0, float2& u1){
  int s0 = lane >> 1, s1 = s0 + 32;
  bool odd = (lane & 1) != 0;
  float t0x = __shfl(a0.x, s0), t0y = __shfl(a0.y, s0);
  float t1x = __shfl(a1.x, s0), t1y = __shfl(a1.y, s0);
  u0 = odd ? make_float2(t1x, t1y) : make_float2(t0x, t0y);
  float q0x = __shfl(a0.x, s1), q0y = __shfl(a0.y, s1);
  float q1x = __shfl(a1.x, s1), q1y = __shfl(a1.y, s1);
  u1 = odd ? make_float2(q1x, q1y) : make_float2(q0x, q0y);
}

// ---- (B,HW,C) -> (B,C,HW) transpose, float4 both phases ----
__global__ __launch_bounds__(256) void k_transpose(const float* __restrict__ x, float* __restrict__ x2){
  __shared__ float tile[64][68];
  int b = blockIdx.z;
  int hw0 = blockIdx.x*64, c0 = blockIdx.y*64;
  int tid = threadIdx.x;
  #pragma unroll
  for (int q=0;q<4;q++){
    int p = tid + q*256;            // 0..1023 covers 64hw x 16 float4
    int hw = p >> 4, c4 = (p & 15) << 2;
    float4 v = *(const float4*)&x[((size_t)b*HW_ + hw0 + hw)*C_ + c0 + c4];
    *(float4*)&tile[hw][c4] = v;
  }
  __syncthreads();
  #pragma unroll
  for (int q=0;q<4;q++){
    int p = tid + q*256;
    int c = p >> 4, h4 = (p & 15) << 2;
    float4 v = make_float4(tile[h4][c], tile[h4+1][c], tile[h4+2][c], tile[h4+3][c]);
    *(float4*)&x2[((size_t)b*C_ + c0 + c)*HW_ + hw0 + h4] = v;
  }
}

// ---- counts + transposed band-id table: bid_t[kx*128 + ky] ----
__global__ __launch_bounds__(256) void k_counts(float* __restrict__ counts, unsigned char* __restrict__ bid_t){
  int tid = threadIdx.x;
  float acc[6] = {0,0,0,0,0,0};
  for (int p = tid; p < F_; p += 256){
    int kx = p >> 7, ky = p & 127;
    int bnd = band_of(ky, kx);
    bid_t[p] = (unsigned char)bnd;
    #pragma unroll
    for (int n=0;n<6;n++) acc[n] += (bnd==n) ? 1.0f : 0.0f;
  }
  __shared__ float red[6][256];
  #pragma unroll
  for (int n=0;n<6;n++) red[n][tid] = acc[n];
  __syncthreads();
  for (int s=128; s>0; s>>=1){
    if (tid < s){
      #pragma unroll
      for (int n=0;n<6;n++) red[n][tid] += red[n][tid+s];
    }
    __syncthreads();
  }
  if (tid < 6) counts[tid] = fmaxf(red[tid][0], 1.0f);
}

// ---- convert W matrices to bf16 planes ----
__global__ __launch_bounds__(256) void k_wbf16(const float* __restrict__ wre, const float* __restrict__ wim,
                                               const float* __restrict__ lw,
                                               short* __restrict__ Wre, short* __restrict__ Wim,
                                               short* __restrict__ WL){
  int c = blockIdx.x, tid = threadIdx.x, plane = blockIdx.y;
  int idx = c*C_ + tid;
  if (plane == 0)      Wre[idx] = f2bf(wre[idx]);
  else if (plane == 1) Wim[idx] = f2bf(wim[idx]);
  else                 WL[idx]  = f2bf(lw[idx]);
}

// ---- FUSED forward: row rFFT (wave-shuffle) -> LDS tile -> col FFT + ortho + band-gate ----
// one block per slice (b,c); 8 waves; X1t intermediate eliminated.
__global__ __launch_bounds__(512) void k_fwd(const float* __restrict__ x2, float2* __restrict__ Xft,
                                             const float* __restrict__ counts, const unsigned char* __restrict__ bid_t,
                                             const float* __restrict__ w1, const float* __restrict__ b1,
                                             const float* __restrict__ w2, const float* __restrict__ b2,
                                             float* __restrict__ alpha){
  __shared__ float2 lt[65*129];     // [kx][y], stride 129 float2
  __shared__ float red[6][8];
  __shared__ float means[6], h[128];
  int tid = threadIdx.x;
  int lane = tid & 63, wv = tid >> 6;   // 8 waves
  float2 stw[6];
  make_stage_tw(stw, lane);
  float sn128, cs128;
  sincosf(6.283185307179586f*(float)lane/128.0f, &sn128, &cs128);
  int slice = blockIdx.x;
  const float* img = x2 + (size_t)slice*HW_;
  // phase 1: 128 row rFFTs, wave wv owns rows wv*16..wv*16+15
  #pragma unroll
  for (int i=0; i<16; i++){
    int rr = wv*16 + i;
    float2 y = *(const float2*)(img + rr*128 + lane*2);   // y[m] = x[2m] + i x[2m+1]
    float2 v = wave_fft64<-1>(y, stw, lane);
    int rbk = brev6(lane);
    float2 Yk; Yk.x = __shfl(v.x, rbk); Yk.y = __shfl(v.y, rbk);
    int rbm = brev6((64 - lane) & 63);
    float2 Ym; Ym.x = __shfl(v.x, rbm); Ym.y = __shfl(v.y, rbm);
    // X[k] = 0.5*(s - i*e^{-i th}*d), th = 2 pi k/128
    float sx = Yk.x + Ym.x, sy = Yk.y - Ym.y;
    float dx = Yk.x - Ym.x, dy = Yk.y + Ym.y;
    lt[lane*129 + rr] = make_float2(0.5f*(sx - sn128*dx + cs128*dy),
                                    0.5f*(sy - cs128*dx - sn128*dy));
    if (lane == 0)
      lt[64*129 + rr] = make_float2(Yk.x - Yk.y, 0.0f);   // X[64] = sum_even - sum_odd
  }
  __syncthreads();
  // phase 2: 65 column FFTs (2 elems/lane) + scale + band accumulation
  float2* xout = Xft + (size_t)slice*F_;
  float acc[6] = {0,0,0,0,0,0};
  for (int kx = wv; kx < 65; kx += 8){
    float2 a0 = lt[kx*129 + (lane<<1)];
    float2 a1 = lt[kx*129 + (lane<<1) + 1];
    float2 u0, u1;
    redist2(a0, a1, lane, u0, u1);
    // stage 0 (forward): s = u0+u1; d = (u0-u1)*e^{-2pi i lane/128}
    float2 s = make_float2(u0.x+u1.x, u0.y+u1.y);
    float ddx = u0.x-u1.x, ddy = u0.y-u1.y;
    float2 dw = make_float2(ddx*cs128 + ddy*sn128, ddy*cs128 - ddx*sn128);
    float2 v0 = wave_fft64<-1>(s, stw, lane);
    float2 v1 = wave_fft64<-1>(dw, stw, lane);
    int rb = brev6(lane);
    float ex = __shfl(v0.x, rb), ey = __shfl(v0.y, rb);   // X[2*lane]
    float ox = __shfl(v1.x, rb), oy = __shfl(v1.y, rb);   // X[2*lane+1]
    ex *= 0.0078125f; ey *= 0.0078125f;
    ox *= 0.0078125f; oy *= 0.0078125f;
    *(float4*)(xout + (size_t)kx*128 + (lane<<1)) = make_float4(ex, ey, ox, oy);
    float me = __fsqrt_rn(ex*ex + ey*ey);
    float mo = __fsqrt_rn(ox*ox + oy*oy);
    int be = (int)bid_t[kx*128 + (lane<<1)];
    int bo = (int)bid_t[kx*128 + (lane<<1) + 1];
    #pragma unroll
    for (int n=0;n<6;n++) acc[n] += ((be==n) ? me : 0.0f) + ((bo==n) ? mo : 0.0f);
  }
  #pragma unroll
  for (int n=0;n<6;n++){
    float v = acc[n];
    #pragma unroll
    for (int off=32; off>0; off>>=1) v += __shfl_xor(v, off);
    if (lane == 0) red[n][wv] = v;
  }
  __syncthreads();
  if (tid < 6){
    float t = 0.0f;
    #pragma unroll
    for (int q=0;q<8;q++) t += red[tid][q];
    means[tid] = t / (counts[tid] + 1e-6f);
  }
  __syncthreads();
  if (tid < 128){
    float hv = b1[tid];
    #pragma unroll
    for (int n=0;n<6;n++) hv += means[n]*w1[tid*6+n];
    h[tid] = fmaxf(hv, 0.0f);
  }
  __syncthreads();
  if (tid < 6){
    float o = b2[tid];
    for (int j=0;j<128;j++) o += h[j]*w2[tid*128+j];
    alpha[slice*6 + tid] = sigmoidf_(o);
  }
}

// ---- pack Xft (static 40x72 region) -> Xt planes [b][fp][d] bf16, fp = kx*72+ky ----
__global__ __launch_bounds__(256) void k_xt(const float2* __restrict__ Xft,
                                            short* __restrict__ XtRe, short* __restrict__ XtIm){
  __shared__ short sre[72*130];
  __shared__ short sim[72*130];
  int tid = threadIdx.x;
  int kx = blockIdx.x, d0 = blockIdx.y*128, b = blockIdx.z;
  const float2* xb = Xft + ((size_t)(b*C_ + d0))*F_ + (size_t)kx*128;
  for (int p = tid; p < 72*128; p += 256){
    int d = p / 72, ky = p - d*72;
    float2 v = xb[(size_t)d*F_ + ky];
    sre[ky*130 + d] = f2bf(v.x);
    sim[ky*130 + d] = f2bf(v.y);
  }
  __syncthreads();
  short* dre = XtRe + ((size_t)b*FP_ + (size_t)kx*72)*C_ + d0;
  short* dim_ = XtIm + ((size_t)b*FP_ + (size_t)kx*72)*C_ + d0;
  for (int p = tid; p < 72*128; p += 256){
    int ky = p >> 7, d = p & 127;
    dre[(size_t)ky*C_ + d] = sre[ky*130 + d];
    dim_[(size_t)ky*C_ + d] = sim[ky*130 + d];
  }
}

// ---- MFMA complex channel mix: mappedP[c][fp] = sum_d W[c][d] * X[fp][d] ----
__global__ __launch_bounds__(256) void k_mix_mfma(const short* __restrict__ Wre, const short* __restrict__ Wim,
                                                  const short* __restrict__ XtRe, const short* __restrict__ XtIm,
                                                  const float* __restrict__ kxp, const float* __restrict__ kyp,
                                                  float2* __restrict__ mappedP){
  __shared__ short Are[64][36], Aim[64][36], Bre[64][36], Bim[64][36];
  int tid = threadIdx.x;
  int fp0 = blockIdx.x*64, c0 = blockIdx.y*64, b = blockIdx.z;
  int lane = tid & 63, w = tid >> 6;
  int mt = (w >> 1)*32, nt = (w & 1)*32;
  f32x16 accre = {0.f,0.f,0.f,0.f,0.f,0.f,0.f,0.f,0.f,0.f,0.f,0.f,0.f,0.f,0.f,0.f};
  f32x16 accim = {0.f,0.f,0.f,0.f,0.f,0.f,0.f,0.f,0.f,0.f,0.f,0.f,0.f,0.f,0.f,0.f};
  const short* xrb = XtRe + ((size_t)b*FP_ + fp0)*C_;
  const short* xib = XtIm + ((size_t)b*FP_ + fp0)*C_;
  int row4 = tid >> 2, part = tid & 3;
  for (int kc=0; kc<8; kc++){
    int d0 = kc*32;
    __syncthreads();
    lds_store8(&Are[row4][part*8], *(const bf16x8*)&Wre[(c0+row4)*C_ + d0 + part*8]);
    lds_store8(&Aim[row4][part*8], *(const bf16x8*)&Wim[(c0+row4)*C_ + d0 + part*8]);
    lds_store8(&Bre[row4][part*8], *(const bf16x8*)&xrb[(size_t)row4*C_ + d0 + part*8]);
    lds_store8(&Bim[row4][part*8], *(const bf16x8*)&xib[(size_t)row4*C_ + d0 + part*8]);
    __syncthreads();
    #pragma unroll
    for (int ks=0; ks<2; ks++){
      int koff = ks*16 + (lane>>5)*8;
      bf16x8 are = lds_frag(&Are[mt + (lane&31)][koff]);
      bf16x8 aim = lds_frag(&Aim[mt + (lane&31)][koff]);
      bf16x8 bre = lds_frag(&Bre[nt + (lane&31)][koff]);
      bf16x8 bim = lds_frag(&Bim[nt + (lane&31)][koff]);
      bf16x8 naim;
      { union { bf16x8 v; unsigned u[4]; } t1, t2; t1.v = aim;
        #pragma unroll
        for (int j=0;j<4;j++) t2.u[j] = t1.u[j] ^ 0x80008000u;
        naim = t2.v; }
      accre = __builtin_amdgcn_mfma_f32_32x32x16_bf16(are,  bre, accre, 0,0,0);
      accre = __builtin_amdgcn_mfma_f32_32x32x16_bf16(naim, bim, accre, 0,0,0);
      accim = __builtin_amdgcn_mfma_f32_32x32x16_bf16(are,  bim, accim, 0,0,0);
      accim = __builtin_amdgcn_mfma_f32_32x32x16_bf16(aim,  bre, accim, 0,0,0);
    }
  }
  float rowlim = floorf(sigmoidf_(kxp[0])*128.0f);
  float collim = floorf(sigmoidf_(kyp[0])*65.0f);
  int n = fp0 + nt + (lane & 31);
  int ky = n % 72, kx = n / 72;
  bool live = ((float)ky < rowlim) && ((float)kx < collim);
  #pragma unroll
  for (int reg=0; reg<16; reg++){
    int r = (reg & 3) + 8*(reg >> 2) + 4*(lane >> 5);
    int c = c0 + mt + r;
    if (live)
      mappedP[((size_t)(b*C_ + c))*FP_ + n] = make_float2(accre[reg], accim[reg]);
  }
}

// ---- MFMA pointwise: xcs[c][hw] = sum_d lin_w[c][d] * x[hw][d] + lin_b[c] ----
__global__ __launch_bounds__(256) void k_pw_mfma(const float* __restrict__ x, const short* __restrict__ WL,
                                                  const float* __restrict__ lb, float* __restrict__ xcs){
  __shared__ short As[64][36], Bs[64][36];
  int tid = threadIdx.x;
  int hw0 = blockIdx.x*64, c0 = blockIdx.y*64, b = blockIdx.z;
  int lane = tid & 63, w = tid >> 6;
  int mt = (w >> 1)*32, nt = (w & 1)*32;
  f32x16 acc = {0.f,0.f,0.f,0.f,0.f,0.f,0.f,0.f,0.f,0.f,0.f,0.f,0.f,0.f,0.f,0.f};
  const float* xb = x + ((size_t)b*HW_ + hw0)*C_;
  int row4 = tid >> 2, part = tid & 3;
  for (int kc=0; kc<8; kc++){
    int d0 = kc*32;
    __syncthreads();
    lds_store8(&As[row4][part*8], *(const bf16x8*)&WL[(c0+row4)*C_ + d0 + part*8]);
    {
      const float* src = &xb[(size_t)row4*C_ + d0 + part*8];
      float4 va = *(const float4*)src;
      float4 vb = *(const float4*)(src+4);
      bf16x8 bv;
      bv[0]=f2bf(va.x); bv[1]=f2bf(va.y); bv[2]=f2bf(va.z); bv[3]=f2bf(va.w);
      bv[4]=f2bf(vb.x); bv[5]=f2bf(vb.y); bv[6]=f2bf(vb.z); bv[7]=f2bf(vb.w);
      lds_store8(&Bs[row4][part*8], bv);
    }
    __syncthreads();
    #pragma unroll
    for (int ks=0; ks<2; ks++){
      int koff = ks*16 + (lane>>5)*8;
      bf16x8 a  = lds_frag(&As[mt + (lane&31)][koff]);
      bf16x8 bb = lds_frag(&Bs[nt + (lane&31)][koff]);
      acc = __builtin_amdgcn_mfma_f32_32x32x16_bf16(a, bb, acc, 0,0,0);
    }
  }
  int n = hw0 + nt + (lane & 31);
  #pragma unroll
  for (int reg=0; reg<16; reg++){
    int r = (reg & 3) + 8*(reg >> 2) + 4*(lane >> 5);
    int c = c0 + mt + r;
    xcs[((size_t)(b*C_ + c))*HW_ + n] = acc[reg] + lb[c];
  }
}

// ---- inverse col FFT (wave-shuffle) with fused alpha-blend; in place on Xft -> Y1t ----
__global__ __launch_bounds__(256) void k_inv_cols(float2* __restrict__ XftY, const float2* __restrict__ mappedP,
                                                  const float* __restrict__ alpha, const unsigned char* __restrict__ bid_t,
                                                  const float* __restrict__ kxp, const float* __restrict__ kyp){
  __shared__ float al[6];
  int tid = threadIdx.x;
  int lane = tid & 63, wv = tid >> 6;
  int slice = blockIdx.x;
  float2 stw[6];
  make_stage_tw(stw, lane);
  float sn128, cs128;
  sincosf(6.283185307179586f*(float)lane/128.0f, &sn128, &cs128);
  if (tid < 6) al[tid] = alpha[slice*6 + tid];
  float rowlim = floorf(sigmoidf_(kxp[0])*128.0f);
  float collim = floorf(sigmoidf_(kyp[0])*65.0f);
  __syncthreads();
  float2* xfb = XftY + (size_t)slice*F_;
  const float2* mpb = mappedP + (size_t)slice*FP_;
  for (int kx = wv; kx < 65; kx += 4){
    float4 rv = *(const float4*)(xfb + (size_t)kx*128 + (lane<<1));
    int ky0 = lane << 1;
    float a_e = al[(int)bid_t[kx*128 + ky0]];
    float a_o = al[(int)bid_t[kx*128 + ky0 + 1]];
    bool cok  = ((float)kx < collim);
    bool in_e = cok && ((float)ky0 < rowlim);
    bool in_o = cok && ((float)(ky0+1) < rowlim);
    float2 ve, vo;
    if (in_e){
      float4 mv = *(const float4*)(mpb + (size_t)kx*72 + ky0);
      ve = make_float2(mv.x*a_e, mv.y*a_e);
      vo = in_o ? make_float2(mv.z*a_o, mv.w*a_o)
                : make_float2(rv.z*(1.0f-a_o), rv.w*(1.0f-a_o));
    } else {
      ve = make_float2(rv.x*(1.0f-a_e), rv.y*(1.0f-a_e));
      vo = make_float2(rv.z*(1.0f-a_o), rv.w*(1.0f-a_o));
    }
    float2 u0, u1;
    redist2(ve, vo, lane, u0, u1);
    // stage 0 (inverse): s = u0+u1; d = (u0-u1)*e^{+2pi i lane/128}
    float2 s = make_float2(u0.x+u1.x, u0.y+u1.y);
    float ddx = u0.x-u1.x, ddy = u0.y-u1.y;
    float2 dw = make_float2(ddx*cs128 - ddy*sn128, ddx*sn128 + ddy*cs128);
    float2 v0 = wave_fft64<1>(s, stw, lane);
    float2 v1 = wave_fft64<1>(dw, stw, lane);
    int rb = brev6(lane);
    float4 outv;
    outv.x = __shfl(v0.x, rb); outv.y = __shfl(v0.y, rb);   // z[2*lane]
    outv.z = __shfl(v1.x, rb); outv.w = __shfl(v1.y, rb);   // z[2*lane+1]
    *(float4*)(xfb + (size_t)kx*128 + (lane<<1)) = outv;
  }
}

// ---- inverse row c2r via wave-shuffle 64-pt FFT + fused depthwise 3x3 conv + xcs -> sbuf ----
// Y1t is column-major [kx*128 + y]; staged through an LDS tile for row access.
// conv input from global via per-lane register windows + wave shuffles.
__global__ __launch_bounds__(256,6) void k_inv_rows(const float2* __restrict__ Y1t, const float* __restrict__ xcs,
                                                    const float* __restrict__ x2, const float* __restrict__ cw,
                                                    float* __restrict__ sbuf){
  __shared__ float2 ytile[65*33];
  int tid = threadIdx.x;
  int lane = tid & 63, wv = tid >> 6;
  float2 stw[6];
  make_stage_tw(stw, lane);
  float sn128, cs128;
  sincosf(6.283185307179586f*(float)lane/128.0f, &sn128, &cs128);
  int slice = blockIdx.x >> 2;
  int ch = slice & 255;
  int r0 = (blockIdx.x & 3) * 32;
  const float* img = x2 + (size_t)slice*HW_;
  // preload all 10 conv rows for this wave's 8-row strip (issued before LDS staging -> latency overlap)
  int base = r0 + wv*8;
  float2 rows[10];
  #pragma unroll
  for (int i=0;i<10;i++){
    int gr = base - 1 + i;
    rows[i] = ((unsigned)gr < 128u) ? *(const float2*)(img + (size_t)gr*128 + (lane<<1))
                                    : make_float2(0.0f, 0.0f);
  }
  const float2* ysrc = Y1t + (size_t)slice*F_ + r0;
  for (int p = tid; p < 65*32; p += 256){
    int kx = p >> 5, rr = p & 31;
    ytile[kx*33 + rr] = ysrc[(size_t)kx*128 + rr];
  }
  float w9[9];
  #pragma unroll
  for (int k=0;k<9;k++) w9[k] = cw[ch*9+k];
  __syncthreads();
  size_t gbase = (size_t)slice*HW_ + (size_t)r0*128;
  #pragma unroll
  for (int i=0;i<8;i++){
    int row = wv*8 + i;
    // Y[k] = 0.5*(X[k]+conj(X[64-k])) + 0.5*i*e^{+i th_k}*(X[k]-conj(X[64-k])), th_k = 2 pi k/128
    float2 a = ytile[lane*33 + row];
    float2 b = ytile[(64-lane)*33 + row];
    if (lane == 0){ a.y = 0.0f; b.y = 0.0f; }   // force Im(X[0]) = Im(X[64]) = 0
    float sx = a.x + b.x, sy = a.y - b.y;
    float dx = a.x - b.x, dy = a.y + b.y;
    float2 yk = make_float2(0.5f*(sx - sn128*dx - cs128*dy),
                            0.5f*(sy + cs128*dx - sn128*dy));
    float2 v = wave_fft64<1>(yk, stw, lane);
    // un-bit-reverse: lane m holds z[m]; x[2m] = Re/64, x[2m+1] = Im/64
    int rbk = brev6(lane);
    float2 z; z.x = __shfl(v.x, rbk); z.y = __shfl(v.y, rbk);
    int xx = lane << 1;
    float c0 = 0.0f, c1 = 0.0f;
    #pragma unroll
    for (int dy2=0; dy2<3; dy2++){
      float2 cv = rows[i + dy2];
      float l = __shfl_up(cv.y, 1);
      if (lane == 0) l = 0.0f;                 // col -1
      float r = __shfl_down(cv.x, 1);
      if (lane == 63) r = 0.0f;                // col 128
      c0 += l*w9[dy2*3+0] + cv.x*w9[dy2*3+1] + cv.y*w9[dy2*3+2];
      c1 += cv.x*w9[dy2*3+0] + cv.y*w9[dy2*3+1] + r*w9[dy2*3+2];
    }
    size_t g = gbase + (size_t)(row*128 + xx);
    float2 xc = *(const float2*)&xcs[g];
    float2 o;
    o.x = z.x*0.015625f + xc.x + c0;
    o.y = z.y*0.015625f + xc.y + c1;
    *(float2*)&sbuf[g] = o;
  }
}

// ---- fused LN: stats over channels + cond scale/shift + transpose to (B,HW,C) ----
__global__ __launch_bounds__(256) void k_norm(const float* __restrict__ sbuf, const float* __restrict__ timev,
                                              const float* __restrict__ nww, const float* __restrict__ nwb,
                                              const float* __restrict__ nbw, const float* __restrict__ nbb,
                                              float* __restrict__ out){
  __shared__ float tile[64][65];
  __shared__ float p1[64][5], p2[64][5];
  __shared__ float mv[64], rv[64], wv_[256], bv_[256];
  int b = blockIdx.y, hw0 = blockIdx.x*64;
  int tid = threadIdx.x;
  {
    float t = timev[b];
    wv_[tid] = t*nww[tid] + nwb[tid];
    bv_[tid] = t*nbw[tid] + nbb[tid];
  }
  int hwl = tid & 63, cg = tid >> 6;
  const float* p = sbuf + (size_t)b*C_*HW_ + hw0 + hwl;
  float s1 = 0.0f, s2 = 0.0f;
  for (int c = cg*64; c < cg*64 + 64; c++){
    float v = p[(size_t)c*HW_];
    s1 += v; s2 += v*v;
  }
  p1[hwl][cg] = s1; p2[hwl][cg] = s2;
  __syncthreads();
  if (tid < 64){
    float t1 = p1[tid][0] + p1[tid][1] + p1[tid][2] + p1[tid][3];
    float t2 = p2[tid][0] + p2[tid][1] + p2[tid][2] + p2[tid][3];
    float mean = t1 * (1.0f/256.0f);
    float var  = t2 * (1.0f/256.0f) - mean*mean;
    mv[tid] = mean;
    rv[tid] = 1.0f / sqrtf(var + 1e-5f);
  }
  __syncthreads();
  for (int cg2=0; cg2<4; cg2++){
    int c0 = cg2*64;
    #pragma unroll
    for (int q=0;q<16;q++){
      int pp = tid + q*256;
      int cl = pp >> 6, hl = pp & 63;
      tile[cl][hl] = sbuf[((size_t)(b*C_ + c0 + cl))*HW_ + hw0 + hl];
    }
    __syncthreads();
    #pragma unroll
    for (int q=0;q<16;q++){
      int pp = tid + q*256;
      int hl = pp >> 6, cl = pp & 63;
      float v = tile[cl][hl];
      out[((size_t)(b*HW_ + hw0 + hl))*C_ + c0 + cl] = wv_[c0+cl]*((v - mv[hl])*rv[hl]) + bv_[c0+cl];
    }
    __syncthreads();
  }
}

extern "C" void kernel_launch(void* const* d_in, const int* in_sizes, int n_in,
                              void* d_out, int out_size, void* d_ws, size_t ws_size,
                              hipStream_t stream){
  const float* x      = (const float*)d_in[0];
  const float* timev  = (const float*)d_in[1];
  const float* w_real = (const float*)d_in[2];
  const float* w_imag = (const float*)d_in[3];
  const float* conv_w = (const float*)d_in[4];
  const float* lin_w  = (const float*)d_in[5];
  const float* lin_b  = (const float*)d_in[6];
  const float* mlp_w1 = (const float*)d_in[7];
  const float* mlp_b1 = (const float*)d_in[8];
  const float* mlp_w2 = (const float*)d_in[9];
  const float* mlp_b2 = (const float*)d_in[10];
  const float* norm_ww= (const float*)d_in[11];
  const float* norm_wb= (const float*)d_in[12];
  const float* norm_bw= (const float*)d_in[13];
  const float* norm_bb= (const float*)d_in[14];
  const float* kxp    = (const float*)d_in[15];
  const float* kyp    = (const float*)d_in[16];

  // workspace layout (floats) — total 51,093,600 floats = 194.9 MiB
  float* ws = (float*)d_ws;
  float*  alpha  = ws;                               // 6144
  unsigned char* bid_t = (unsigned char*)(ws + 6144);// 8320 B (transposed band table [kx*128+ky])
  float*  counts = ws + 8224;                        // 64
  short*  Wre_bf = (short*)(ws + 139360);            // 65536 shorts (32768 floats)
  short*  Wim_bf = (short*)(ws + 172128);            // 65536 shorts
  short*  WL_bf  = (short*)(ws + 204896);            // 65536 shorts
  float*  x2     = ws + 237664;                      // 16,777,216 (live until k_inv_rows: conv input)
  float2* Xft    = (float2*)(ws + 17014880);         // 17,039,360 floats (Xft, then Y1t in-place)
  float*  CbF    = ws + 34054240;                    // 17,039,360 floats, multi-use:
  short*  XtRe   = (short*)CbF;                      //   Xt bf16 planes [b][2880][256]
  short*  XtIm   = (short*)(CbF + 1474560);
  float2* mappedP= (float2*)(CbF + 2949120);         //   packed mapped [b][c][2880] (5,898,240 floats)
  float*  sb     = CbF + 8847360;                    //   final sum (16,777,216) — disjoint from mappedP
  float*  xcs    = (float*)d_out;                    // pointwise output, scratch in d_out
  float*  out    = (float*)d_out;

  k_transpose    <<<dim3(256, 4, B_), 256, 0, stream>>>(x, x2);
  k_counts       <<<1, 256, 0, stream>>>(counts, bid_t);
  k_wbf16        <<<dim3(256, 3), 256, 0, stream>>>(w_real, w_imag, lin_w, Wre_bf, Wim_bf, WL_bf);
  k_fwd          <<<1024, 512, 0, stream>>>(x2, Xft, counts, bid_t, mlp_w1, mlp_b1, mlp_w2, mlp_b2, alpha);
  k_xt           <<<dim3(40, 2, B_), 256, 0, stream>>>(Xft, XtRe, XtIm);
  k_pw_mfma      <<<dim3(256, 4, B_), 256, 0, stream>>>(x, WL_bf, lin_b, xcs);
  k_mix_mfma     <<<dim3(45, 4, B_), 256, 0, stream>>>(Wre_bf, Wim_bf, XtRe, XtIm, kxp, kyp, mappedP);
  k_inv_cols     <<<1024, 256, 0, stream>>>(Xft, mappedP, alpha, bid_t, kxp, kyp);
  k_inv_rows     <<<4096, 256, 0, stream>>>((const float2*)Xft, xcs, x2, conv_w, sb);
  k_norm         <<<dim3(256, B_), 256, 0, stream>>>(sb, timev, norm_ww, norm_wb, norm_bw, norm_bb, out);
}

// Round 9
// 410.371 us; speedup vs baseline: 1.0760x; 1.0760x over previous
//
#include <hip/hip_runtime.h>
#include <math.h>

#define B_ 4
#define C_ 256
#define RES_ 128
#define HW_ 16384
#define WF_ 65
#define F_ 8320
#define FP_ 2880   // packed masked-freq grid: 40 cols x 72 rows, fp = kx*72 + ky (covers runtime 36x71)

typedef __attribute__((ext_vector_type(8))) short bf16x8;
typedef __attribute__((ext_vector_type(16))) float f32x16;

__device__ __forceinline__ int brev6(int j){ return (int)(__brev((unsigned)j) >> 26); }

__device__ __forceinline__ short f2bf(float f){
  unsigned u = __float_as_uint(f);
  unsigned r = (u + 0x7FFFu + ((u>>16)&1u)) >> 16;
  return (short)r;
}

__device__ __forceinline__ bf16x8 lds_frag(const short* p){
  union { bf16x8 v; int2 d[2]; } u;
  u.d[0] = *(const int2*)p;
  u.d[1] = *(const int2*)(p+4);
  return u.v;
}
__device__ __forceinline__ void lds_store8(short* p, bf16x8 v){
  union { bf16x8 v; int2 d[2]; } u; u.v = v;
  *(int2*)p = u.d[0]; *(int2*)(p+4) = u.d[1];
}

// ---- band id, bit-exact vs numpy float32 ----
__device__ __forceinline__ int band_of(int row, int col){
  float yy = __fdiv_rn((float)row, 127.0f);
  float xx = __fdiv_rn((float)col, 64.0f);
  float rr = __fsqrt_rn(__fadd_rn(__fmul_rn(yy,yy), __fmul_rn(xx,xx)));
  float rm = __fadd_rn(__fsqrt_rn(2.0f), 1e-8f);
  float rn = __fdiv_rn(rr, rm);
  int b = (int)floorf(__fmul_rn(rn, 6.0f));
  return b > 5 ? 5 : b;
}

__device__ __forceinline__ float sigmoidf_(float v){ return 1.0f/(1.0f+expf(-v)); }

// ---- wave-synchronous 64-pt radix-2 DIF FFT, one complex value per lane ----
// Output bit-reversed across lanes: result for index r lives at lane brev6(r).
template<int SGN>
__device__ __forceinline__ float2 wave_fft64(float2 v, const float2* stw, int lane){
  #pragma unroll
  for (int s=0; s<6; s++){
    int H = 32 >> s;
    float ox = __shfl_xor(v.x, H);
    float oy = __shfl_xor(v.y, H);
    bool hi = (lane & H) != 0;
    float2 w = stw[s];
    float ws = (SGN < 0) ? -w.y : w.y;
    float sx = v.x + ox, sy = v.y + oy;
    float dx = ox - v.x, dy = oy - v.y;   // (a - b) on the hi lane
    float rx = dx*w.x - dy*ws;
    float ry = dx*ws + dy*w.x;
    v.x = hi ? rx : sx;
    v.y = hi ? ry : sy;
  }
  return v;
}

// per-lane stage twiddles: identical float values to a 128-entry table at even indices
__device__ __forceinline__ void make_stage_tw(float2* stw, int lane){
  #pragma unroll
  for (int s=0; s<6; s++){
    int H = 32 >> s;
    int t = (lane & (H-1)) << s;
    float sn, cs;
    sincosf(6.283185307179586f*(float)t/64.0f, &sn, &cs);
    stw[s] = make_float2(cs, sn);
  }
}

// ---- (B,HW,C) -> (B,C,HW) transpose, float4 both phases ----
__global__ __launch_bounds__(256) void k_transpose(const float* __restrict__ x, float* __restrict__ x2){
  __shared__ float tile[64][68];
  int b = blockIdx.z;
  int hw0 = blockIdx.x*64, c0 = blockIdx.y*64;
  int tid = threadIdx.x;
  #pragma unroll
  for (int q=0;q<4;q++){
    int p = tid + q*256;            // 0..1023 covers 64hw x 16 float4
    int hw = p >> 4, c4 = (p & 15) << 2;
    float4 v = *(const float4*)&x[((size_t)b*HW_ + hw0 + hw)*C_ + c0 + c4];
    *(float4*)&tile[hw][c4] = v;
  }
  __syncthreads();
  #pragma unroll
  for (int q=0;q<4;q++){
    int p = tid + q*256;
    int c = p >> 4, h4 = (p & 15) << 2;
    float4 v = make_float4(tile[h4][c], tile[h4+1][c], tile[h4+2][c], tile[h4+3][c]);
    *(float4*)&x2[((size_t)b*C_ + c0 + c)*HW_ + hw0 + h4] = v;
  }
}

// ---- counts + transposed band-id table: bid_t[kx*128 + ky] ----
__global__ __launch_bounds__(256) void k_counts(float* __restrict__ counts, unsigned char* __restrict__ bid_t){
  int tid = threadIdx.x;
  float acc[6] = {0,0,0,0,0,0};
  for (int p = tid; p < F_; p += 256){
    int kx = p >> 7, ky = p & 127;
    int bnd = band_of(ky, kx);
    bid_t[p] = (unsigned char)bnd;
    #pragma unroll
    for (int n=0;n<6;n++) acc[n] += (bnd==n) ? 1.0f : 0.0f;
  }
  __shared__ float red[6][256];
  #pragma unroll
  for (int n=0;n<6;n++) red[n][tid] = acc[n];
  __syncthreads();
  for (int s=128; s>0; s>>=1){
    if (tid < s){
      #pragma unroll
      for (int n=0;n<6;n++) red[n][tid] += red[n][tid+s];
    }
    __syncthreads();
  }
  if (tid < 6) counts[tid] = fmaxf(red[tid][0], 1.0f);
}

// ---- convert W matrices to bf16 planes ----
__global__ __launch_bounds__(256) void k_wbf16(const float* __restrict__ wre, const float* __restrict__ wim,
                                               const float* __restrict__ lw,
                                               short* __restrict__ Wre, short* __restrict__ Wim,
                                               short* __restrict__ WL){
  int c = blockIdx.x, tid = threadIdx.x, plane = blockIdx.y;
  int idx = c*C_ + tid;
  if (plane == 0)      Wre[idx] = f2bf(wre[idx]);
  else if (plane == 1) Wim[idx] = f2bf(wim[idx]);
  else                 WL[idx]  = f2bf(lw[idx]);
}

// ---- FUSED forward: row rFFT (wave-shuffle) -> [y][kx] LDS planes -> col FFT + ortho + band-gate ----
// one block per slice (b,c); 8 waves; conflict-free stride-65 planes, no redistribution shuffles.
__global__ __launch_bounds__(512) void k_fwd(const float* __restrict__ x2, float2* __restrict__ Xft,
                                             const float* __restrict__ counts, const unsigned char* __restrict__ bid_t,
                                             const float* __restrict__ w1, const float* __restrict__ b1,
                                             const float* __restrict__ w2, const float* __restrict__ b2,
                                             float* __restrict__ alpha){
  __shared__ float ltx[128*65];     // [y][kx], stride 65 (odd -> conflict-free)
  __shared__ float lty[128*65];
  __shared__ float red[6][8];
  __shared__ float means[6], h[128];
  int tid = threadIdx.x;
  int lane = tid & 63, wv = tid >> 6;   // 8 waves
  float2 stw[6];
  make_stage_tw(stw, lane);
  float sn128, cs128;
  sincosf(6.283185307179586f*(float)lane/128.0f, &sn128, &cs128);
  int slice = blockIdx.x;
  const float* img = x2 + (size_t)slice*HW_;
  // phase 1: 128 row rFFTs, wave wv owns rows wv*16..wv*16+15; preload all 16 rows first
  float2 yv[16];
  #pragma unroll
  for (int i=0;i<16;i++){
    int rr = wv*16 + i;
    yv[i] = *(const float2*)(img + rr*128 + lane*2);      // y[m] = x[2m] + i x[2m+1]
  }
  #pragma unroll
  for (int i=0; i<16; i++){
    int rr = wv*16 + i;
    float2 v = wave_fft64<-1>(yv[i], stw, lane);
    int rbk = brev6(lane);
    float2 Yk; Yk.x = __shfl(v.x, rbk); Yk.y = __shfl(v.y, rbk);
    int rbm = brev6((64 - lane) & 63);
    float2 Ym; Ym.x = __shfl(v.x, rbm); Ym.y = __shfl(v.y, rbm);
    // X[k] = 0.5*(s - i*e^{-i th}*d), th = 2 pi k/128
    float sx = Yk.x + Ym.x, sy = Yk.y - Ym.y;
    float dx = Yk.x - Ym.x, dy = Yk.y + Ym.y;
    ltx[rr*65 + lane] = 0.5f*(sx - sn128*dx + cs128*dy);
    lty[rr*65 + lane] = 0.5f*(sy - cs128*dx - sn128*dy);
    if (lane == 0){
      ltx[rr*65 + 64] = Yk.x - Yk.y;   // X[64] = sum_even - sum_odd
      lty[rr*65 + 64] = 0.0f;
    }
  }
  __syncthreads();
  // phase 2: 65 column FFTs; lane l directly loads y=l and y=l+64 (no redistribution)
  float2* xout = Xft + (size_t)slice*F_;
  float acc[6] = {0,0,0,0,0,0};
  for (int kx = wv; kx < 65; kx += 8){
    float2 u0 = make_float2(ltx[lane*65 + kx],      lty[lane*65 + kx]);
    float2 u1 = make_float2(ltx[(lane+64)*65 + kx], lty[(lane+64)*65 + kx]);
    // stage 0 (forward): s = u0+u1; d = (u0-u1)*e^{-2pi i lane/128}
    float2 s = make_float2(u0.x+u1.x, u0.y+u1.y);
    float ddx = u0.x-u1.x, ddy = u0.y-u1.y;
    float2 dw = make_float2(ddx*cs128 + ddy*sn128, ddy*cs128 - ddx*sn128);
    float2 v0 = wave_fft64<-1>(s, stw, lane);
    float2 v1 = wave_fft64<-1>(dw, stw, lane);
    int rb = brev6(lane);
    float ex = __shfl(v0.x, rb), ey = __shfl(v0.y, rb);   // X[2*lane]
    float ox = __shfl(v1.x, rb), oy = __shfl(v1.y, rb);   // X[2*lane+1]
    ex *= 0.0078125f; ey *= 0.0078125f;
    ox *= 0.0078125f; oy *= 0.0078125f;
    *(float4*)(xout + (size_t)kx*128 + (lane<<1)) = make_float4(ex, ey, ox, oy);
    float me = __fsqrt_rn(ex*ex + ey*ey);
    float mo = __fsqrt_rn(ox*ox + oy*oy);
    int be = (int)bid_t[kx*128 + (lane<<1)];
    int bo = (int)bid_t[kx*128 + (lane<<1) + 1];
    #pragma unroll
    for (int n=0;n<6;n++) acc[n] += ((be==n) ? me : 0.0f) + ((bo==n) ? mo : 0.0f);
  }
  #pragma unroll
  for (int n=0;n<6;n++){
    float v = acc[n];
    #pragma unroll
    for (int off=32; off>0; off>>=1) v += __shfl_xor(v, off);
    if (lane == 0) red[n][wv] = v;
  }
  __syncthreads();
  if (tid < 6){
    float t = 0.0f;
    #pragma unroll
    for (int q=0;q<8;q++) t += red[tid][q];
    means[tid] = t / (counts[tid] + 1e-6f);
  }
  __syncthreads();
  if (tid < 128){
    float hv = b1[tid];
    #pragma unroll
    for (int n=0;n<6;n++) hv += means[n]*w1[tid*6+n];
    h[tid] = fmaxf(hv, 0.0f);
  }
  __syncthreads();
  if (tid < 6){
    float o = b2[tid];
    for (int j=0;j<128;j++) o += h[j]*w2[tid*128+j];
    alpha[slice*6 + tid] = sigmoidf_(o);
  }
}

// ---- pack Xft (static 40x72 region) -> Xt planes [b][fp][d] bf16, fp = kx*72+ky ----
__global__ __launch_bounds__(256) void k_xt(const float2* __restrict__ Xft,
                                            short* __restrict__ XtRe, short* __restrict__ XtIm){
  __shared__ short sre[72*130];
  __shared__ short sim[72*130];
  int tid = threadIdx.x;
  int kx = blockIdx.x, d0 = blockIdx.y*128, b = blockIdx.z;
  const float2* xb = Xft + ((size_t)(b*C_ + d0))*F_ + (size_t)kx*128;
  for (int p = tid; p < 72*128; p += 256){
    int d = p / 72, ky = p - d*72;
    float2 v = xb[(size_t)d*F_ + ky];
    sre[ky*130 + d] = f2bf(v.x);
    sim[ky*130 + d] = f2bf(v.y);
  }
  __syncthreads();
  short* dre = XtRe + ((size_t)b*FP_ + (size_t)kx*72)*C_ + d0;
  short* dim_ = XtIm + ((size_t)b*FP_ + (size_t)kx*72)*C_ + d0;
  for (int p = tid; p < 72*128; p += 256){
    int ky = p >> 7, d = p & 127;
    dre[(size_t)ky*C_ + d] = sre[ky*130 + d];
    dim_[(size_t)ky*C_ + d] = sim[ky*130 + d];
  }
}

// ---- MFMA complex channel mix: mappedP[c][fp] = sum_d W[c][d] * X[fp][d] ----
__global__ __launch_bounds__(256) void k_mix_mfma(const short* __restrict__ Wre, const short* __restrict__ Wim,
                                                  const short* __restrict__ XtRe, const short* __restrict__ XtIm,
                                                  const float* __restrict__ kxp, const float* __restrict__ kyp,
                                                  float2* __restrict__ mappedP){
  __shared__ short Are[64][36], Aim[64][36], Bre[64][36], Bim[64][36];
  int tid = threadIdx.x;
  int fp0 = blockIdx.x*64, c0 = blockIdx.y*64, b = blockIdx.z;
  int lane = tid & 63, w = tid >> 6;
  int mt = (w >> 1)*32, nt = (w & 1)*32;
  f32x16 accre = {0.f,0.f,0.f,0.f,0.f,0.f,0.f,0.f,0.f,0.f,0.f,0.f,0.f,0.f,0.f,0.f};
  f32x16 accim = {0.f,0.f,0.f,0.f,0.f,0.f,0.f,0.f,0.f,0.f,0.f,0.f,0.f,0.f,0.f,0.f};
  const short* xrb = XtRe + ((size_t)b*FP_ + fp0)*C_;
  const short* xib = XtIm + ((size_t)b*FP_ + fp0)*C_;
  int row4 = tid >> 2, part = tid & 3;
  for (int kc=0; kc<8; kc++){
    int d0 = kc*32;
    __syncthreads();
    lds_store8(&Are[row4][part*8], *(const bf16x8*)&Wre[(c0+row4)*C_ + d0 + part*8]);
    lds_store8(&Aim[row4][part*8], *(const bf16x8*)&Wim[(c0+row4)*C_ + d0 + part*8]);
    lds_store8(&Bre[row4][part*8], *(const bf16x8*)&xrb[(size_t)row4*C_ + d0 + part*8]);
    lds_store8(&Bim[row4][part*8], *(const bf16x8*)&xib[(size_t)row4*C_ + d0 + part*8]);
    __syncthreads();
    #pragma unroll
    for (int ks=0; ks<2; ks++){
      int koff = ks*16 + (lane>>5)*8;
      bf16x8 are = lds_frag(&Are[mt + (lane&31)][koff]);
      bf16x8 aim = lds_frag(&Aim[mt + (lane&31)][koff]);
      bf16x8 bre = lds_frag(&Bre[nt + (lane&31)][koff]);
      bf16x8 bim = lds_frag(&Bim[nt + (lane&31)][koff]);
      bf16x8 naim;
      { union { bf16x8 v; unsigned u[4]; } t1, t2; t1.v = aim;
        #pragma unroll
        for (int j=0;j<4;j++) t2.u[j] = t1.u[j] ^ 0x80008000u;
        naim = t2.v; }
      accre = __builtin_amdgcn_mfma_f32_32x32x16_bf16(are,  bre, accre, 0,0,0);
      accre = __builtin_amdgcn_mfma_f32_32x32x16_bf16(naim, bim, accre, 0,0,0);
      accim = __builtin_amdgcn_mfma_f32_32x32x16_bf16(are,  bim, accim, 0,0,0);
      accim = __builtin_amdgcn_mfma_f32_32x32x16_bf16(aim,  bre, accim, 0,0,0);
    }
  }
  float rowlim = floorf(sigmoidf_(kxp[0])*128.0f);
  float collim = floorf(sigmoidf_(kyp[0])*65.0f);
  int n = fp0 + nt + (lane & 31);
  int ky = n % 72, kx = n / 72;
  bool live = ((float)ky < rowlim) && ((float)kx < collim);
  #pragma unroll
  for (int reg=0; reg<16; reg++){
    int r = (reg & 3) + 8*(reg >> 2) + 4*(lane >> 5);
    int c = c0 + mt + r;
    if (live)
      mappedP[((size_t)(b*C_ + c))*FP_ + n] = make_float2(accre[reg], accim[reg]);
  }
}

// ---- MFMA pointwise: xcs[c][hw] = sum_d lin_w[c][d] * x[hw][d] + lin_b[c] ----
__global__ __launch_bounds__(256) void k_pw_mfma(const float* __restrict__ x, const short* __restrict__ WL,
                                                  const float* __restrict__ lb, float* __restrict__ xcs){
  __shared__ short As[64][36], Bs[64][36];
  int tid = threadIdx.x;
  int hw0 = blockIdx.x*64, c0 = blockIdx.y*64, b = blockIdx.z;
  int lane = tid & 63, w = tid >> 6;
  int mt = (w >> 1)*32, nt = (w & 1)*32;
  f32x16 acc = {0.f,0.f,0.f,0.f,0.f,0.f,0.f,0.f,0.f,0.f,0.f,0.f,0.f,0.f,0.f,0.f};
  const float* xb = x + ((size_t)b*HW_ + hw0)*C_;
  int row4 = tid >> 2, part = tid & 3;
  for (int kc=0; kc<8; kc++){
    int d0 = kc*32;
    __syncthreads();
    lds_store8(&As[row4][part*8], *(const bf16x8*)&WL[(c0+row4)*C_ + d0 + part*8]);
    {
      const float* src = &xb[(size_t)row4*C_ + d0 + part*8];
      float4 va = *(const float4*)src;
      float4 vb = *(const float4*)(src+4);
      bf16x8 bv;
      bv[0]=f2bf(va.x); bv[1]=f2bf(va.y); bv[2]=f2bf(va.z); bv[3]=f2bf(va.w);
      bv[4]=f2bf(vb.x); bv[5]=f2bf(vb.y); bv[6]=f2bf(vb.z); bv[7]=f2bf(vb.w);
      lds_store8(&Bs[row4][part*8], bv);
    }
    __syncthreads();
    #pragma unroll
    for (int ks=0; ks<2; ks++){
      int koff = ks*16 + (lane>>5)*8;
      bf16x8 a  = lds_frag(&As[mt + (lane&31)][koff]);
      bf16x8 bb = lds_frag(&Bs[nt + (lane&31)][koff]);
      acc = __builtin_amdgcn_mfma_f32_32x32x16_bf16(a, bb, acc, 0,0,0);
    }
  }
  int n = hw0 + nt + (lane & 31);
  #pragma unroll
  for (int reg=0; reg<16; reg++){
    int r = (reg & 3) + 8*(reg >> 2) + 4*(lane >> 5);
    int c = c0 + mt + r;
    xcs[((size_t)(b*C_ + c))*HW_ + n] = acc[reg] + lb[c];
  }
}

// ---- FUSED inverse: col FFT + alpha-blend -> [y][kx] LDS planes -> row c2r + conv + xcs -> sbuf ----
// one block per slice; 8 waves; per-element blend at ky=l and ky=l+64 (no redistribution shuffles).
__global__ __launch_bounds__(512) void k_inv(const float2* __restrict__ Xft, const float2* __restrict__ mappedP,
                                             const float* __restrict__ alpha, const unsigned char* __restrict__ bid_t,
                                             const float* __restrict__ kxp, const float* __restrict__ kyp,
                                             const float* __restrict__ xcs, const float* __restrict__ x2,
                                             const float* __restrict__ cw, float* __restrict__ sbuf){
  __shared__ float ltx[128*65];     // [y][kx], stride 65
  __shared__ float lty[128*65];
  __shared__ float al[6];
  int tid = threadIdx.x;
  int lane = tid & 63, wv = tid >> 6;
  float2 stw[6];
  make_stage_tw(stw, lane);
  float sn128, cs128;
  sincosf(6.283185307179586f*(float)lane/128.0f, &sn128, &cs128);
  int slice = blockIdx.x;
  int ch = slice & 255;
  if (tid < 6) al[tid] = alpha[slice*6 + tid];
  float rowlim = floorf(sigmoidf_(kxp[0])*128.0f);
  float collim = floorf(sigmoidf_(kyp[0])*65.0f);
  // preload conv rows for this wave's 16-row strip (before barriers -> latency overlap)
  const float* img = x2 + (size_t)slice*HW_;
  int base = wv*16;
  float2 rows[18];
  #pragma unroll
  for (int i=0;i<18;i++){
    int gr = base - 1 + i;
    rows[i] = ((unsigned)gr < 128u) ? *(const float2*)(img + (size_t)gr*128 + (lane<<1))
                                    : make_float2(0.0f, 0.0f);
  }
  float w9[9];
  #pragma unroll
  for (int k=0;k<9;k++) w9[k] = cw[ch*9+k];
  __syncthreads();   // al visible
  // phase 1: 65 inverse column FFTs with fused blend; lane l owns ky=l and ky=l+64
  const float2* xfb = Xft + (size_t)slice*F_;
  const float2* mpb = mappedP + (size_t)slice*FP_;
  for (int kx = wv; kx < 65; kx += 8){
    float2 rlo = xfb[(size_t)kx*128 + lane];
    float2 rhi = xfb[(size_t)kx*128 + lane + 64];
    float a_lo = al[(int)bid_t[kx*128 + lane]];
    float a_hi = al[(int)bid_t[kx*128 + lane + 64]];
    bool cok   = ((float)kx < collim);
    bool in_lo = cok && ((float)lane < rowlim);
    bool in_hi = cok && ((float)(lane+64) < rowlim);
    float2 u0, u1;
    if (in_lo){ float2 mv = mpb[(size_t)kx*72 + lane];      u0 = make_float2(mv.x*a_lo, mv.y*a_lo); }
    else      { float om = 1.0f - a_lo;                      u0 = make_float2(rlo.x*om,  rlo.y*om);  }
    if (in_hi){ float2 mv = mpb[(size_t)kx*72 + lane + 64]; u1 = make_float2(mv.x*a_hi, mv.y*a_hi); }
    else      { float om = 1.0f - a_hi;                      u1 = make_float2(rhi.x*om,  rhi.y*om);  }
    // stage 0 (inverse): s = u0+u1; d = (u0-u1)*e^{+2pi i lane/128}
    float2 s = make_float2(u0.x+u1.x, u0.y+u1.y);
    float ddx = u0.x-u1.x, ddy = u0.y-u1.y;
    float2 dw = make_float2(ddx*cs128 - ddy*sn128, ddx*sn128 + ddy*cs128);
    float2 v0 = wave_fft64<1>(s, stw, lane);
    float2 v1 = wave_fft64<1>(dw, stw, lane);
    int m = brev6(lane);              // lane holds z[2m] (=v0) and z[2m+1] (=v1)
    ltx[(2*m)*65 + kx]   = v0.x; lty[(2*m)*65 + kx]   = v0.y;
    ltx[(2*m+1)*65 + kx] = v1.x; lty[(2*m+1)*65 + kx] = v1.y;
  }
  __syncthreads();
  // phase 2: 128 inverse row c2r FFTs + conv + xcs sum
  size_t gbase = (size_t)slice*HW_;
  #pragma unroll
  for (int i=0;i<16;i++){
    int row = base + i;
    // Y[k] = 0.5*(X[k]+conj(X[64-k])) + 0.5*i*e^{+i th_k}*(X[k]-conj(X[64-k])), th_k = 2 pi k/128
    float2 a = make_float2(ltx[row*65 + lane],        lty[row*65 + lane]);
    float2 b = make_float2(ltx[row*65 + 64 - lane],   lty[row*65 + 64 - lane]);
    if (lane == 0){ a.y = 0.0f; b.y = 0.0f; }   // force Im(X[0]) = Im(X[64]) = 0
    float sx = a.x + b.x, sy = a.y - b.y;
    float dx = a.x - b.x, dy = a.y + b.y;
    float2 yk = make_float2(0.5f*(sx - sn128*dx - cs128*dy),
                            0.5f*(sy + cs128*dx - sn128*dy));
    float2 v = wave_fft64<1>(yk, stw, lane);
    // un-bit-reverse: lane m holds z[m]; x[2m] = Re/64, x[2m+1] = Im/64
    int rbk = brev6(lane);
    float2 z; z.x = __shfl(v.x, rbk); z.y = __shfl(v.y, rbk);
    int xx = lane << 1;
    float c0 = 0.0f, c1 = 0.0f;
    #pragma unroll
    for (int dy2=0; dy2<3; dy2++){
      float2 cv = rows[i + dy2];
      float l = __shfl_up(cv.y, 1);
      if (lane == 0) l = 0.0f;                 // col -1
      float r = __shfl_down(cv.x, 1);
      if (lane == 63) r = 0.0f;                // col 128
      c0 += l*w9[dy2*3+0] + cv.x*w9[dy2*3+1] + cv.y*w9[dy2*3+2];
      c1 += cv.x*w9[dy2*3+0] + cv.y*w9[dy2*3+1] + r*w9[dy2*3+2];
    }
    size_t g = gbase + (size_t)(row*128 + xx);
    float2 xc = *(const float2*)&xcs[g];
    float2 o;
    o.x = z.x*0.015625f + xc.x + c0;
    o.y = z.y*0.015625f + xc.y + c1;
    *(float2*)&sbuf[g] = o;
  }
}

// ---- fused LN: stats over channels + cond scale/shift + transpose to (B,HW,C) ----
__global__ __launch_bounds__(256) void k_norm(const float* __restrict__ sbuf, const float* __restrict__ timev,
                                              const float* __restrict__ nww, const float* __restrict__ nwb,
                                              const float* __restrict__ nbw, const float* __restrict__ nbb,
                                              float* __restrict__ out){
  __shared__ float tile[64][65];
  __shared__ float p1[64][5], p2[64][5];
  __shared__ float mv[64], rv[64], wv_[256], bv_[256];
  int b = blockIdx.y, hw0 = blockIdx.x*64;
  int tid = threadIdx.x;
  {
    float t = timev[b];
    wv_[tid] = t*nww[tid] + nwb[tid];
    bv_[tid] = t*nbw[tid] + nbb[tid];
  }
  int hwl = tid & 63, cg = tid >> 6;
  const float* p = sbuf + (size_t)b*C_*HW_ + hw0 + hwl;
  float s1 = 0.0f, s2 = 0.0f;
  for (int c = cg*64; c < cg*64 + 64; c++){
    float v = p[(size_t)c*HW_];
    s1 += v; s2 += v*v;
  }
  p1[hwl][cg] = s1; p2[hwl][cg] = s2;
  __syncthreads();
  if (tid < 64){
    float t1 = p1[tid][0] + p1[tid][1] + p1[tid][2] + p1[tid][3];
    float t2 = p2[tid][0] + p2[tid][1] + p2[tid][2] + p2[tid][3];
    float mean = t1 * (1.0f/256.0f);
    float var  = t2 * (1.0f/256.0f) - mean*mean;
    mv[tid] = mean;
    rv[tid] = 1.0f / sqrtf(var + 1e-5f);
  }
  __syncthreads();
  for (int cg2=0; cg2<4; cg2++){
    int c0 = cg2*64;
    #pragma unroll
    for (int q=0;q<16;q++){
      int pp = tid + q*256;
      int cl = pp >> 6, hl = pp & 63;
      tile[cl][hl] = sbuf[((size_t)(b*C_ + c0 + cl))*HW_ + hw0 + hl];
    }
    __syncthreads();
    #pragma unroll
    for (int q=0;q<16;q++){
      int pp = tid + q*256;
      int hl = pp >> 6, cl = pp & 63;
      float v = tile[cl][hl];
      out[((size_t)(b*HW_ + hw0 + hl))*C_ + c0 + cl] = wv_[c0+cl]*((v - mv[hl])*rv[hl]) + bv_[c0+cl];
    }
    __syncthreads();
  }
}

extern "C" void kernel_launch(void* const* d_in, const int* in_sizes, int n_in,
                              void* d_out, int out_size, void* d_ws, size_t ws_size,
                              hipStream_t stream){
  const float* x      = (const float*)d_in[0];
  const float* timev  = (const float*)d_in[1];
  const float* w_real = (const float*)d_in[2];
  const float* w_imag = (const float*)d_in[3];
  const float* conv_w = (const float*)d_in[4];
  const float* lin_w  = (const float*)d_in[5];
  const float* lin_b  = (const float*)d_in[6];
  const float* mlp_w1 = (const float*)d_in[7];
  const float* mlp_b1 = (const float*)d_in[8];
  const float* mlp_w2 = (const float*)d_in[9];
  const float* mlp_b2 = (const float*)d_in[10];
  const float* norm_ww= (const float*)d_in[11];
  const float* norm_wb= (const float*)d_in[12];
  const float* norm_bw= (const float*)d_in[13];
  const float* norm_bb= (const float*)d_in[14];
  const float* kxp    = (const float*)d_in[15];
  const float* kyp    = (const float*)d_in[16];

  float* ws = (float*)d_ws;
  float*  alpha  = ws;                               // 6144
  unsigned char* bid_t = (unsigned char*)(ws + 6144);// 8320 B (transposed band table [kx*128+ky])
  float*  counts = ws + 8224;                        // 64
  short*  Wre_bf = (short*)(ws + 139360);            // 65536 shorts (32768 floats)
  short*  Wim_bf = (short*)(ws + 172128);            // 65536 shorts
  short*  WL_bf  = (short*)(ws + 204896);            // 65536 shorts
  float*  x2     = ws + 237664;                      // 16,777,216 (live until k_inv: conv input)
  float2* Xft    = (float2*)(ws + 17014880);         // 17,039,360 floats (read-only after k_fwd)
  float*  CbF    = ws + 34054240;                    // multi-use:
  short*  XtRe   = (short*)CbF;                      //   Xt bf16 planes [b][2880][256]
  short*  XtIm   = (short*)(CbF + 1474560);
  float2* mappedP= (float2*)(CbF + 2949120);         //   packed mapped [b][c][2880] (5,898,240 floats)
  float*  sb     = CbF + 8847360;                    //   final sum (16,777,216) — disjoint from mappedP
  float*  xcs    = (float*)d_out;                    // pointwise output, scratch in d_out
  float*  out    = (float*)d_out;

  k_transpose    <<<dim3(256, 4, B_), 256, 0, stream>>>(x, x2);
  k_counts       <<<1, 256, 0, stream>>>(counts, bid_t);
  k_wbf16        <<<dim3(256, 3), 256, 0, stream>>>(w_real, w_imag, lin_w, Wre_bf, Wim_bf, WL_bf);
  k_fwd          <<<1024, 512, 0, stream>>>(x2, Xft, counts, bid_t, mlp_w1, mlp_b1, mlp_w2, mlp_b2, alpha);
  k_xt           <<<dim3(40, 2, B_), 256, 0, stream>>>(Xft, XtRe, XtIm);
  k_pw_mfma      <<<dim3(256, 4, B_), 256, 0, stream>>>(x, WL_bf, lin_b, xcs);
  k_mix_mfma     <<<dim3(45, 4, B_), 256, 0, stream>>>(Wre_bf, Wim_bf, XtRe, XtIm, kxp, kyp, mappedP);
  k_inv          <<<1024, 512, 0, stream>>>(Xft, mappedP, alpha, bid_t, kxp, kyp, xcs, x2, conv_w, sb);
  k_norm         <<<dim3(256, B_), 256, 0, stream>>>(sb, timev, norm_ww, norm_wb, norm_bw, norm_bb, out);
}